// Round 8
// baseline (209.009 us; speedup 1.0000x reference)
//
#include <hip/hip_runtime.h>
#include <hip/hip_bf16.h>

#define GAT_N 8192
#define GAT_K 256
#define GAT_D 64
#define GAT_ALPHA 0.2f
#define GAT_FILL 1e-15f

typedef float f32x4 __attribute__((ext_vector_type(4)));
typedef short bf16x8 __attribute__((ext_vector_type(8)));

static __device__ __forceinline__ unsigned f2bf_u(float x) {
  unsigned u = __float_as_uint(x);
  u += 0x7FFFu + ((u >> 16) & 1u);
  return u >> 16;
}

static __device__ __forceinline__ float rfl(float x) {
  return __uint_as_float(__builtin_amdgcn_readfirstlane(__float_as_uint(x)));
}

// ---------------------------------------------------------------------------
// Kernel 1: register-tiled Wh = h @ W (validated round 4, unchanged).
// ---------------------------------------------------------------------------
__global__ __launch_bounds__(256) void k_prep(const float* __restrict__ h,
                                              const float* __restrict__ W,
                                              const float* __restrict__ av,
                                              float* __restrict__ s_src,
                                              float* __restrict__ s_dst,
                                              short* __restrict__ WhT,
                                              float* __restrict__ bmax) {
  __shared__ short T[4][64][8];
  __shared__ float wmLds[4];
  const int tid = threadIdx.x;
  const int wv = tid >> 6, lane = tid & 63;
  const int r0 = blockIdx.x * 32 + wv * 8;

  float acc[8], acc2[8];
#pragma unroll
  for (int r = 0; r < 8; ++r) { acc[r] = 0.f; acc2[r] = 0.f; }

  for (int kc = 0; kc < GAT_K; kc += 32) {
    float Wreg[32];
#pragma unroll
    for (int e = 0; e < 32; ++e) Wreg[e] = W[(size_t)(kc + e) * GAT_D + lane];
#pragma unroll
    for (int r = 0; r < 8; ++r) {
      const f32x4* h4 = (const f32x4*)(h + (size_t)(r0 + r) * GAT_K + kc);
#pragma unroll
      for (int q = 0; q < 8; ++q) {
        f32x4 hv = h4[q];
        acc[r] += hv[0] * Wreg[4 * q + 0];
        acc2[r] += hv[1] * Wreg[4 * q + 1];
        acc[r] += hv[2] * Wreg[4 * q + 2];
        acc2[r] += hv[3] * Wreg[4 * q + 3];
      }
    }
  }

  const float a_s = av[lane];
  const float a_d = av[64 + lane];
  float wmax = -3.0e38f;
#pragma unroll
  for (int r = 0; r < 8; ++r) {
    const float accf = acc[r] + acc2[r];
    T[wv][lane][r] = (short)f2bf_u(accf);
    float vs = accf * a_s, vd = accf * a_d;
#pragma unroll
    for (int off = 32; off > 0; off >>= 1) {
      vs += __shfl_xor(vs, off);
      vd += __shfl_xor(vd, off);
    }
    if (lane == 0) { s_src[r0 + r] = vs; s_dst[r0 + r] = vd; }
    wmax = fmaxf(wmax, vd);
  }
  bf16x8 vt = *(const bf16x8*)&T[wv][lane][0];
  *(bf16x8*)(WhT + (size_t)lane * GAT_N + r0) = vt;

  if (lane == 0) wmLds[wv] = wmax;
  __syncthreads();
  if (tid == 0) {
    bmax[blockIdx.x] = fmaxf(fmaxf(wmLds[0], wmLds[1]), fmaxf(wmLds[2], wmLds[3]));
  }
}

// ---------------------------------------------------------------------------
// Kernel 2: IDENTICAL structure to round 7, but A addressing is parameterized
// by (rowStride, chunkStride) held in SGPRs:
//   real run : rowStride=GAT_N, chunkStride=JB  -> streams all 256 MB of A
//   probe run: rowStride=0,     chunkStride=0   -> same instruction stream,
//              all "A" loads hit one 4 KB L1-resident block (zero HBM for A)
// The probe writes to ws scratch; the real run writes d_out (same as R7).
// dur_R8 - dur_R7 = attn_compute_only + node overhead  (the measurement).
// ---------------------------------------------------------------------------
#define BM 16
#define JB 1024
#define NCHUNK (GAT_N / JB)
#define NWAVE 8

__global__ __launch_bounds__(512, 4) void k_attn(
    const float* __restrict__ A,
    long rowStride, long chunkStride,
    const float* __restrict__ s_src,
    const float* __restrict__ s_dst,
    const short* __restrict__ WhT,
    const float* __restrict__ bmax,
    float* __restrict__ out) {
  __shared__ char smem[65536];  // 2 x [16][1024] bf16 swizzled tiles; epilogue reuse

  const int tid = threadIdx.x;
  const int wv = tid >> 6, lane = tid & 63;
  const int rsub = lane & 15, kg = lane >> 4;
  const int i0 = blockIdx.x * BM;
  const int par = wv >> 2;          // wave-uniform: 0 for tid<256, 1 for tid>=256
  const int cth = tid & 255;        // column-thread index within parity group

  // global max of s_dst from 256 per-block maxima
  float bm = fmaxf(fmaxf(bmax[lane], bmax[lane + 64]),
                   fmaxf(bmax[lane + 128], bmax[lane + 192]));
#pragma unroll
  for (int off = 32; off > 0; off >>= 1) bm = fmaxf(bm, __shfl_xor(bm, off));
  const float tmax = bm;

  // softmax constants for this thread's 8 rows (row = 2*s + par, wave-uniform)
  float e1_[8], e2_[8], c_[8];
#pragma unroll
  for (int s = 0; s < 8; ++s) {
    float sc = s_src[i0 + 2 * s + par];
    float x0 = sc + tmax;
    float m = fmaxf(fmaxf(x0, GAT_ALPHA * x0), GAT_FILL);
    e1_[s] = rfl(sc - m);
    e2_[s] = rfl(GAT_ALPHA * sc - m);
    c_[s] = rfl(__expf(GAT_FILL - m));
  }

  bf16x8 ones;
#pragma unroll
  for (int e = 0; e < 8; ++e) ones[e] = (short)0x3F80;

  f32x4 acc0 = {0.f, 0.f, 0.f, 0.f};
  f32x4 acc1 = {0.f, 0.f, 0.f, 0.f};
  f32x4 acc2 = {0.f, 0.f, 0.f, 0.f};
  f32x4 acc3 = {0.f, 0.f, 0.f, 0.f};
  f32x4 accl = {0.f, 0.f, 0.f, 0.f};

  const short* pb0 = WhT + (size_t)(0 * 16 + rsub) * GAT_N;
  const short* pb1 = WhT + (size_t)(1 * 16 + rsub) * GAT_N;
  const short* pb2 = WhT + (size_t)(2 * 16 + rsub) * GAT_N;
  const short* pb3 = WhT + (size_t)(3 * 16 + rsub) * GAT_N;

  // A addressing, stride-parameterized (strides live in SGPRs; identical VALU)
  const float* Abase = A + (size_t)(i0 + par) * rowStride + cth * 4;
  auto aaddr = [&](int g) {
    return Abase + (size_t)((g & 7) * 2) * rowStride + (size_t)(g >> 3) * chunkStride;
  };

  f32x4 buf[4];
#pragma unroll
  for (int g = 0; g < 4; ++g) buf[g] = *(const f32x4*)aaddr(g);

  for (int chunk = 0; chunk < NCHUNK; ++chunk) {
    const int jc = chunk * JB;
    const int tile = (chunk & 1) << 15;  // 0 or 32768
    const f32x4 t = *(const f32x4*)(s_dst + jc + cth * 4);

    // ---- stage phase: 8 steps, 4-deep pipeline ----
#pragma unroll
    for (int s = 0; s < 8; ++s) {
      const int g = chunk * 8 + s;
      f32x4 av = buf[g & 3];
      if (g + 4 < 64) buf[(g + 4) & 3] = *(const f32x4*)aaddr(g + 4);
      const float e1 = e1_[s], e2 = e2_[s], cc = c_[s];
      unsigned pk[4];
#pragma unroll
      for (int e = 0; e < 4; ++e) {
        float arg = fmaxf(t[e] + e1, fmaf(GAT_ALPHA, t[e], e2));
        float pe = __expf(arg);
        pe = (av[e] > 0.f) ? pe : cc;
        pk[e] = f2bf_u(pe);
      }
      uint2 w;
      w.x = pk[0] | (pk[1] << 16);
      w.y = pk[2] | (pk[3] << 16);
      const int row = 2 * s + par;
      *(uint2*)(&smem[tile + (row << 11) + (((cth << 3)) ^ ((row & 7) << 4))]) = w;
    }
    __syncthreads();  // tile ready; also orders MFMA(c-1) before stage(c+1)

    // ---- MFMA phase: wave wv consumes cols [jc + wv*128, +128) ----
#pragma unroll
    for (int kq = 0; kq < 4; ++kq) {
      const int cbyte = (wv << 8) + (kq << 6) + (kg << 4);
      bf16x8 af = *(const bf16x8*)(&smem[tile + (rsub << 11) + (cbyte ^ ((rsub & 7) << 4))]);
      const int bcol = jc + (wv << 7) + (kq << 5) + (kg << 3);
      bf16x8 b0 = *(const bf16x8*)(pb0 + bcol);
      bf16x8 b1 = *(const bf16x8*)(pb1 + bcol);
      bf16x8 b2 = *(const bf16x8*)(pb2 + bcol);
      bf16x8 b3 = *(const bf16x8*)(pb3 + bcol);
      acc0 = __builtin_amdgcn_mfma_f32_16x16x32_bf16(af, b0, acc0, 0, 0, 0);
      acc1 = __builtin_amdgcn_mfma_f32_16x16x32_bf16(af, b1, acc1, 0, 0, 0);
      acc2 = __builtin_amdgcn_mfma_f32_16x16x32_bf16(af, b2, acc2, 0, 0, 0);
      acc3 = __builtin_amdgcn_mfma_f32_16x16x32_bf16(af, b3, acc3, 0, 0, 0);
      accl = __builtin_amdgcn_mfma_f32_16x16x32_bf16(af, ones, accl, 0, 0, 0);
    }
  }

  __syncthreads();  // all MFMA done before smem reuse

  // ---- epilogue: exact cross-wave combine + ELU (smem reused) ----
  float* lds_o = (float*)smem;            // [8][16][64] f32 = 32 KB
  float* lds_l = (float*)(smem + 32768);  // [8][16]
#pragma unroll
  for (int r = 0; r < 4; ++r) {
    const int orow = kg * 4 + r;  // C/D layout: col = lane&15, row = kg*4+reg
    lds_o[wv * 1024 + orow * 64 + 0 * 16 + rsub] = acc0[r];
    lds_o[wv * 1024 + orow * 64 + 1 * 16 + rsub] = acc1[r];
    lds_o[wv * 1024 + orow * 64 + 2 * 16 + rsub] = acc2[r];
    lds_o[wv * 1024 + orow * 64 + 3 * 16 + rsub] = acc3[r];
    if (rsub == 0) lds_l[wv * 16 + orow] = accl[r];
  }
  __syncthreads();

  for (int idx = tid; idx < BM * GAT_D; idx += 512) {
    const int r = idx >> 6, c = idx & 63;
    float o = 0.f, ll = 0.f;
#pragma unroll
    for (int w = 0; w < NWAVE; ++w) {
      o += lds_o[w * 1024 + r * 64 + c];
      ll += lds_l[w * 16 + r];
    }
    float val = o / ll;
    out[(size_t)(i0 + r) * GAT_D + c] = (val > 0.f) ? val : (__expf(val) - 1.f);
  }
}

// ---------------------------------------------------------------------------
extern "C" void kernel_launch(void* const* d_in, const int* in_sizes, int n_in,
                              void* d_out, int out_size, void* d_ws, size_t ws_size,
                              hipStream_t stream) {
  const float* h = (const float*)d_in[0];
  const float* A = (const float*)d_in[1];
  const float* W = (const float*)d_in[2];
  const float* a = (const float*)d_in[3];
  float* out = (float*)d_out;

  // ws layout: [0,1K) bmax | [4K,+32K) s_src | [36864,+32K) s_dst | [69632,+1M) WhT
  //            [2M,+16K) probe "A" block (poisoned bytes, values irrelevant)
  //            [4M,+2M)  probe scratch output
  const size_t need = 4194304 + 2097152;
  if (ws_size < need) return;
  float* bmax = (float*)d_ws;
  float* s_src = (float*)((char*)d_ws + 4096);
  float* s_dst = (float*)((char*)d_ws + 36864);
  short* WhT = (short*)((char*)d_ws + 69632);
  const float* Aprobe = (const float*)((char*)d_ws + 2097152);
  float* out_scratch = (float*)((char*)d_ws + 4194304);

  k_prep<<<dim3(256), dim3(256), 0, stream>>>(h, W, a, s_src, s_dst, WhT, bmax);
  // PROBE: identical instruction stream, zero HBM traffic for A (L1-resident)
  k_attn<<<dim3(GAT_N / BM), dim3(512), 0, stream>>>(
      Aprobe, 0L, 0L, s_src, s_dst, WhT, bmax, out_scratch);
  // REAL: exactly round 7's k_attn
  k_attn<<<dim3(GAT_N / BM), dim3(512), 0, stream>>>(
      A, (long)GAT_N, (long)JB, s_src, s_dst, WhT, bmax, out);
}

// Round 9
// 131.371 us; speedup vs baseline: 1.5910x; 1.5910x over previous
//
#include <hip/hip_runtime.h>
#include <hip/hip_bf16.h>

#define GAT_N 8192
#define GAT_K 256
#define GAT_D 64
#define GAT_ALPHA 0.2f
#define GAT_FILL 1e-15f

typedef float f32x4 __attribute__((ext_vector_type(4)));
typedef short bf16x8 __attribute__((ext_vector_type(8)));

static __device__ __forceinline__ unsigned f2bf_u(float x) {
  unsigned u = __float_as_uint(x);
  u += 0x7FFFu + ((u >> 16) & 1u);
  return u >> 16;
}

static __device__ __forceinline__ float rfl(float x) {
  return __uint_as_float(__builtin_amdgcn_readfirstlane(__float_as_uint(x)));
}

// ---------------------------------------------------------------------------
// Kernel 1: register-tiled Wh = h @ W (validated round 4, unchanged).
// ---------------------------------------------------------------------------
__global__ __launch_bounds__(256) void k_prep(const float* __restrict__ h,
                                              const float* __restrict__ W,
                                              const float* __restrict__ av,
                                              float* __restrict__ s_src,
                                              float* __restrict__ s_dst,
                                              short* __restrict__ WhT,
                                              float* __restrict__ bmax) {
  __shared__ short T[4][64][8];
  __shared__ float wmLds[4];
  const int tid = threadIdx.x;
  const int wv = tid >> 6, lane = tid & 63;
  const int r0 = blockIdx.x * 32 + wv * 8;

  float acc[8], acc2[8];
#pragma unroll
  for (int r = 0; r < 8; ++r) { acc[r] = 0.f; acc2[r] = 0.f; }

  for (int kc = 0; kc < GAT_K; kc += 32) {
    float Wreg[32];
#pragma unroll
    for (int e = 0; e < 32; ++e) Wreg[e] = W[(size_t)(kc + e) * GAT_D + lane];
#pragma unroll
    for (int r = 0; r < 8; ++r) {
      const f32x4* h4 = (const f32x4*)(h + (size_t)(r0 + r) * GAT_K + kc);
#pragma unroll
      for (int q = 0; q < 8; ++q) {
        f32x4 hv = h4[q];
        acc[r] += hv[0] * Wreg[4 * q + 0];
        acc2[r] += hv[1] * Wreg[4 * q + 1];
        acc[r] += hv[2] * Wreg[4 * q + 2];
        acc2[r] += hv[3] * Wreg[4 * q + 3];
      }
    }
  }

  const float a_s = av[lane];
  const float a_d = av[64 + lane];
  float wmax = -3.0e38f;
#pragma unroll
  for (int r = 0; r < 8; ++r) {
    const float accf = acc[r] + acc2[r];
    T[wv][lane][r] = (short)f2bf_u(accf);
    float vs = accf * a_s, vd = accf * a_d;
#pragma unroll
    for (int off = 32; off > 0; off >>= 1) {
      vs += __shfl_xor(vs, off);
      vd += __shfl_xor(vd, off);
    }
    if (lane == 0) { s_src[r0 + r] = vs; s_dst[r0 + r] = vd; }
    wmax = fmaxf(wmax, vd);
  }
  bf16x8 vt = *(const bf16x8*)&T[wv][lane][0];
  *(bf16x8*)(WhT + (size_t)lane * GAT_N + r0) = vt;

  if (lane == 0) wmLds[wv] = wmax;
  __syncthreads();
  if (tid == 0) {
    bmax[blockIdx.x] = fmaxf(fmaxf(wmLds[0], wmLds[1]), fmaxf(wmLds[2], wmLds[3]));
  }
}

// ---------------------------------------------------------------------------
// Kernel 2: fused masked-softmax + P@Wh, fixed-shift softmax — FACTORIZED exp.
//   P_edge = (t_j >= -s_r) ? E1_j*F1_r : E2_j*F2_r,  else cc_r
//   E1_j = exp(t_j), E2_j = exp(alpha*t_j)  -- computed ONCE per chunk per
//   thread (shared by all 16 rows: 8x fewer exps); F1/F2/cc wave-uniform
//   SGPRs. bf16 pack via v_cvt_pk (compiler). Double-buffered P tile,
//   one barrier per chunk, 4-deep A-load pipeline (structure = round 7).
// ---------------------------------------------------------------------------
#define BM 16
#define JB 1024
#define NCHUNK (GAT_N / JB)
#define NWAVE 8

__global__ __launch_bounds__(512, 4) void k_attn(
    const float* __restrict__ A,
    const float* __restrict__ s_src,
    const float* __restrict__ s_dst,
    const short* __restrict__ WhT,
    const float* __restrict__ bmax,
    float* __restrict__ out) {
  __shared__ char smem[65536];  // 2 x [16][1024] bf16 swizzled tiles; epilogue reuse

  const int tid = threadIdx.x;
  const int wv = tid >> 6, lane = tid & 63;
  const int rsub = lane & 15, kg = lane >> 4;
  const int i0 = blockIdx.x * BM;
  const int par = wv >> 2;          // wave-uniform: 0 for tid<256, 1 for tid>=256
  const int cth = tid & 255;        // column-thread index within parity group

  // global max of s_dst from 256 per-block maxima
  float bm = fmaxf(fmaxf(bmax[lane], bmax[lane + 64]),
                   fmaxf(bmax[lane + 128], bmax[lane + 192]));
#pragma unroll
  for (int off = 32; off > 0; off >>= 1) bm = fmaxf(bm, __shfl_xor(bm, off));
  const float tmax = bm;

  // per-row wave-uniform constants (rows r = 2*s + par)
  float F1_[8], F2_[8], ns_[8], c_[8];
#pragma unroll
  for (int s = 0; s < 8; ++s) {
    float sc = s_src[i0 + 2 * s + par];
    float x0 = sc + tmax;
    float m = fmaxf(fmaxf(x0, GAT_ALPHA * x0), GAT_FILL);
    F1_[s] = rfl(__expf(sc - m));
    F2_[s] = rfl(__expf(GAT_ALPHA * sc - m));
    ns_[s] = rfl(-sc);
    c_[s] = rfl(__expf(GAT_FILL - m));
  }

  bf16x8 ones;
#pragma unroll
  for (int e = 0; e < 8; ++e) ones[e] = (short)0x3F80;

  f32x4 acc0 = {0.f, 0.f, 0.f, 0.f};
  f32x4 acc1 = {0.f, 0.f, 0.f, 0.f};
  f32x4 acc2 = {0.f, 0.f, 0.f, 0.f};
  f32x4 acc3 = {0.f, 0.f, 0.f, 0.f};
  f32x4 accl = {0.f, 0.f, 0.f, 0.f};

  const short* pb0 = WhT + (size_t)(0 * 16 + rsub) * GAT_N;
  const short* pb1 = WhT + (size_t)(1 * 16 + rsub) * GAT_N;
  const short* pb2 = WhT + (size_t)(2 * 16 + rsub) * GAT_N;
  const short* pb3 = WhT + (size_t)(3 * 16 + rsub) * GAT_N;

  // A addressing: step g (0..63): chunk g>>3, in-chunk step s=g&7,
  // row = 2*s + par, cols [chunk*1024 + cth*4, +4)   (compile-time strides)
  const float* Abase = A + (size_t)(i0 + par) * GAT_N + cth * 4;
  auto aaddr = [&](int g) {
    return Abase + (size_t)((g & 7) * 2) * GAT_N + (size_t)(g >> 3) * JB;
  };

  f32x4 buf[4];
#pragma unroll
  for (int g = 0; g < 4; ++g) buf[g] = *(const f32x4*)aaddr(g);

  for (int chunk = 0; chunk < NCHUNK; ++chunk) {
    const int jc = chunk * JB;
    const int tile = (chunk & 1) << 15;  // 0 or 32768
    const f32x4 t = *(const f32x4*)(s_dst + jc + cth * 4);

    // per-chunk exps, shared across all 16 rows
    f32x4 E1, E2;
#pragma unroll
    for (int e = 0; e < 4; ++e) {
      E1[e] = __expf(t[e]);
      E2[e] = __expf(GAT_ALPHA * t[e]);
    }

    // ---- stage phase: 8 steps, 4-deep load pipeline ----
#pragma unroll
    for (int s = 0; s < 8; ++s) {
      const int g = chunk * 8 + s;
      f32x4 av = buf[g & 3];
      if (g + 4 < 64) buf[(g + 4) & 3] = *(const f32x4*)aaddr(g + 4);
      const float F1 = F1_[s], F2 = F2_[s], negs = ns_[s], cc = c_[s];
      float p[4];
#pragma unroll
      for (int e = 0; e < 4; ++e) {
        float m1 = E1[e] * F1;
        float m2 = E2[e] * F2;
        float psel = (t[e] >= negs) ? m1 : m2;
        p[e] = (av[e] > 0.f) ? psel : cc;
      }
      __hip_bfloat162 pa = __float22bfloat162_rn(float2{p[0], p[1]});
      __hip_bfloat162 pb = __float22bfloat162_rn(float2{p[2], p[3]});
      uint2 w;
      __builtin_memcpy(&w.x, &pa, 4);
      __builtin_memcpy(&w.y, &pb, 4);
      const int row = 2 * s + par;
      *(uint2*)(&smem[tile + (row << 11) + (((cth << 3)) ^ ((row & 7) << 4))]) = w;
    }
    __syncthreads();  // tile ready; also orders MFMA(c-1) before stage(c+1)

    // ---- MFMA phase: wave wv consumes cols [jc + wv*128, +128) ----
#pragma unroll
    for (int kq = 0; kq < 4; ++kq) {
      const int cbyte = (wv << 8) + (kq << 6) + (kg << 4);
      bf16x8 af = *(const bf16x8*)(&smem[tile + (rsub << 11) + (cbyte ^ ((rsub & 7) << 4))]);
      const int bcol = jc + (wv << 7) + (kq << 5) + (kg << 3);
      bf16x8 b0 = *(const bf16x8*)(pb0 + bcol);
      bf16x8 b1 = *(const bf16x8*)(pb1 + bcol);
      bf16x8 b2 = *(const bf16x8*)(pb2 + bcol);
      bf16x8 b3 = *(const bf16x8*)(pb3 + bcol);
      acc0 = __builtin_amdgcn_mfma_f32_16x16x32_bf16(af, b0, acc0, 0, 0, 0);
      acc1 = __builtin_amdgcn_mfma_f32_16x16x32_bf16(af, b1, acc1, 0, 0, 0);
      acc2 = __builtin_amdgcn_mfma_f32_16x16x32_bf16(af, b2, acc2, 0, 0, 0);
      acc3 = __builtin_amdgcn_mfma_f32_16x16x32_bf16(af, b3, acc3, 0, 0, 0);
      accl = __builtin_amdgcn_mfma_f32_16x16x32_bf16(af, ones, accl, 0, 0, 0);
    }
    // no trailing barrier: next stage writes the OTHER tile; the next
    // iteration's barrier orders this MFMA before that tile's re-stage.
  }

  __syncthreads();  // all MFMA done before smem reuse

  // ---- epilogue: exact cross-wave combine + ELU (smem reused) ----
  float* lds_o = (float*)smem;            // [8][16][64] f32 = 32 KB
  float* lds_l = (float*)(smem + 32768);  // [8][16]
#pragma unroll
  for (int r = 0; r < 4; ++r) {
    const int orow = kg * 4 + r;  // C/D layout: col = lane&15, row = kg*4+reg
    lds_o[wv * 1024 + orow * 64 + 0 * 16 + rsub] = acc0[r];
    lds_o[wv * 1024 + orow * 64 + 1 * 16 + rsub] = acc1[r];
    lds_o[wv * 1024 + orow * 64 + 2 * 16 + rsub] = acc2[r];
    lds_o[wv * 1024 + orow * 64 + 3 * 16 + rsub] = acc3[r];
    if (rsub == 0) lds_l[wv * 16 + orow] = accl[r];
  }
  __syncthreads();

  for (int idx = tid; idx < BM * GAT_D; idx += 512) {
    const int r = idx >> 6, c = idx & 63;
    float o = 0.f, ll = 0.f;
#pragma unroll
    for (int w = 0; w < NWAVE; ++w) {
      o += lds_o[w * 1024 + r * 64 + c];
      ll += lds_l[w * 16 + r];
    }
    float val = o / ll;
    out[(size_t)(i0 + r) * GAT_D + c] = (val > 0.f) ? val : (__expf(val) - 1.f);
  }
}

// ---------------------------------------------------------------------------
extern "C" void kernel_launch(void* const* d_in, const int* in_sizes, int n_in,
                              void* d_out, int out_size, void* d_ws, size_t ws_size,
                              hipStream_t stream) {
  const float* h = (const float*)d_in[0];
  const float* A = (const float*)d_in[1];
  const float* W = (const float*)d_in[2];
  const float* a = (const float*)d_in[3];
  float* out = (float*)d_out;

  // ws layout: [0,1K) bmax | [4K,+32K) s_src | [36864,+32K) s_dst | [69632,+1M) WhT
  const size_t need = 69632 + (size_t)GAT_D * GAT_N * 2;
  if (ws_size < need) return;
  float* bmax = (float*)d_ws;
  float* s_src = (float*)((char*)d_ws + 4096);
  float* s_dst = (float*)((char*)d_ws + 36864);
  short* WhT = (short*)((char*)d_ws + 69632);

  k_prep<<<dim3(256), dim3(256), 0, stream>>>(h, W, a, s_src, s_dst, WhT, bmax);
  k_attn<<<dim3(GAT_N / BM), dim3(512), 0, stream>>>(A, s_src, s_dst, WhT, bmax, out);
}